// Round 1
// baseline (78.313 us; speedup 1.0000x reference)
//
#include <hip/hip_runtime.h>
#include <math.h>

// Problem constants (match reference)
#define NTOT   5040000          // NT
#define NFORC  84000            // NF
#define NSUB_  60
#define NSTEPS (NTOT - 1)       // 5,039,999 model steps (it = 0..NT-2)

// Decomposition: each block processes a window of WIN=256*60 steps;
// first WARM steps are redundant warm-up (|a|^4800 < 1e-4 => error < 1e-5).
#define TPB     256
#define SEGS    60              // steps per thread == NSUB => segment spans exactly one forcing interval
#define WIN     (TPB * SEGS)    // 15360
#define WARM    4800            // multiple of 60
#define CHUNK   (WIN - WARM)    // 10560 output steps owned per block
#define TILE    30              // LDS output-staging tile (two tiles per segment)
#define TSTRIDE 31              // padded row stride (odd => conflict-free-ish b64)

__global__ __launch_bounds__(TPB, 2)
void slab_scan_kernel(const float* __restrict__ pk,
                      const float* __restrict__ TAx,
                      const float* __restrict__ TAy,
                      float* __restrict__ out)
{
    __shared__ float2 tb[TPB * TSTRIDE];   // 63,488 B; reused: scan buffer then output tiles

    const int tid = threadIdx.x;
    const int blk = blockIdx.x;

    // model parameters
    const float K0 = expf(pk[0]);
    const float K1 = expf(pk[1]);
    const float ar = 1.0f - 60.0f * K1;    // Re(a)
    const float ai = -60.0f * 1.0e-4f;     // Im(a) = -dt*fc
    const float s  = 60.0f * K0;           // b_t = s * TAi_t

    const int wstart = blk * CHUNK;                 // first output step owned
    const int wend   = min(wstart + CHUNK, NSTEPS); // one past last owned
    const int ws     = max(0, wstart - WARM);       // window start (multiple of 60)

    // ---- forcing for this thread's 60-step segment (one interval, coalesced) ----
    const int itf = ws / NSUB_ + tid;
    const int i0  = min(itf,     NFORC - 1);
    const int i1  = min(itf + 1, NFORC - 1);
    const float x0 = TAx[i0], y0 = TAy[i0];
    const float x1 = TAx[i1], y1 = TAy[i1];
    const float cinv = s * (1.0f / 60.0f);
    const float dxs  = (x1 - x0) * cinv;   // per-substep increment of Re(b)
    const float dys  = (y1 - y0) * cinv;
    const float b0re = s * x0;             // b at aa = 0
    const float b0im = s * y0;

    // ---- pass 1: local carry over 60 steps starting from u = 0 ----
    float ur = 0.f, ui = 0.f;
    {
        float bre = b0re, bim = b0im;
        #pragma unroll
        for (int k = 0; k < SEGS; ++k) {
            float nr = fmaf(ar, ur, fmaf(-ai, ui, bre));
            float ni = fmaf(ar, ui, fmaf( ai, ur, bim));
            ur = nr; ui = ni;
            bre += dxs; bim += dys;
        }
    }

    // ---- powers alpha^(2^k), alpha = a^60 (double precision, negligible cost) ----
    float2 apow[8];
    {
        double br_ = (double)ar, bi_ = (double)ai;
        double prr = 1.0, pii = 0.0;
        int e = SEGS;
        while (e) {
            if (e & 1) { double t = prr*br_ - pii*bi_; pii = prr*bi_ + pii*br_; prr = t; }
            double t = br_*br_ - bi_*bi_; bi_ = 2.0*br_*bi_; br_ = t;
            e >>= 1;
        }
        double cr = prr, ci = pii;
        #pragma unroll
        for (int k = 0; k < 8; ++k) {
            apow[k] = make_float2((float)cr, (float)ci);
            double t = cr*cr - ci*ci; ci = 2.0*cr*ci; cr = t;
        }
    }

    // ---- Hillis-Steele inclusive scan of affine carries (uniform coefficient) ----
    float2 v = make_float2(ur, ui);
    tb[tid] = v;
    __syncthreads();
    #pragma unroll
    for (int k = 0; k < 8; ++k) {
        const int off = 1 << k;
        float2 prev = make_float2(0.f, 0.f);
        if (tid >= off) prev = tb[tid - off];
        __syncthreads();
        v.x = fmaf(apow[k].x, prev.x, fmaf(-apow[k].y, prev.y, v.x));
        v.y = fmaf(apow[k].x, prev.y, fmaf( apow[k].y, prev.x, v.y));
        tb[tid] = v;
        __syncthreads();
    }
    float usr = 0.f, usi = 0.f;
    if (tid > 0) { float2 p = tb[tid - 1]; usr = p.x; usi = p.y; }
    __syncthreads();   // scan region of tb is about to be reused for tiles

    // ---- pass 2: recompute with correct u_start; stage outputs in LDS, drain coalesced ----
    ur = usr; ui = usi;
    float bre = b0re, bim = b0im;
    for (int h = 0; h < SEGS / TILE; ++h) {
        #pragma unroll
        for (int k = 0; k < TILE; ++k) {
            float nr = fmaf(ar, ur, fmaf(-ai, ui, bre));
            float ni = fmaf(ar, ui, fmaf( ai, ur, bim));
            ur = nr; ui = ni;
            bre += dxs; bim += dys;
            tb[tid * TSTRIDE + k] = make_float2(nr, ni);
        }
        __syncthreads();
        // drain 256*30 staged values; thread handles j = tid, tid+256, ...
        {
            int row = tid / TILE;
            int k   = tid - row * TILE;
            for (int i = 0; i < TILE; ++i) {
                float2 w = tb[row * TSTRIDE + k];
                const int o = ws + row * SEGS + h * TILE + k;   // model step index
                if (o >= wstart && o < wend) {
                    out[o + 1]        = w.x;   // real(U[o+1])
                    out[NTOT + o + 1] = w.y;   // imag(U[o+1])
                }
                // j += 256: 256 = 8*30 + 16
                row += 8; k += 16;
                if (k >= TILE) { k -= TILE; row += 1; }
            }
        }
        __syncthreads();
    }

    // U[0] = 0
    if (blk == 0 && tid == 0) { out[0] = 0.f; out[NTOT] = 0.f; }
}

extern "C" void kernel_launch(void* const* d_in, const int* in_sizes, int n_in,
                              void* d_out, int out_size, void* d_ws, size_t ws_size,
                              hipStream_t stream)
{
    const float* pk  = (const float*)d_in[0];
    const float* TAx = (const float*)d_in[1];
    const float* TAy = (const float*)d_in[2];
    float* out = (float*)d_out;

    const int nblocks = (NSTEPS + CHUNK - 1) / CHUNK;   // 478
    slab_scan_kernel<<<dim3(nblocks), dim3(TPB), 0, stream>>>(pk, TAx, TAy, out);
}